// Round 6
// baseline (209.966 us; speedup 1.0000x reference)
//
#include <hip/hip_runtime.h>
#include <math.h>

// Problem constants (from reference)
constexpr int B_ = 16, T_ = 256, D_ = 384, M_ = 2048, F_ = 256, NMEL_ = 80;
constexpr float PACE_ = 1.0f, MAXDUR_ = 75.0f;
constexpr int R_ = B_ * T_;  // 4096 total rows

typedef unsigned short ushort_t;
typedef __attribute__((ext_vector_type(8))) short bf16x8;
typedef __attribute__((ext_vector_type(4))) float f32x4_;

static __device__ __forceinline__ ushort_t f2bf(float x) {
    union { float f; unsigned int u; } v; v.f = x;
    const unsigned int r = v.u + 0x7fffu + ((v.u >> 16) & 1u);  // RNE
    return (ushort_t)(r >> 16);
}
static __device__ __forceinline__ float bf2f(ushort_t h) {
    union { float f; unsigned int u; } v; v.u = ((unsigned int)h) << 16;
    return v.f;
}

// ---------------------------------------------------------------------------
// Weight repack device job: w[F_,CIN,3] fp32 -> bf16 16x16x32 B-frag order:
//   p[ ((k*(F_/16)+fn)*(CIN/32)+c)*512 + lane*8 + j ]
//     = w[f=fn*16+(lane&15)][d=c*32+(lane>>4)*8+j][k]
// ---------------------------------------------------------------------------
template <int CIN>
static __device__ void repack_job(int bx, const float* __restrict__ w,
                                  ushort_t* __restrict__ p)
{
    constexpr int NC = CIN / 32;
    const int gid = bx * 256 + threadIdx.x;   // over 3*F_*CIN/8
    const int lane = gid & 63;
    int rest = gid >> 6;
    const int c = rest % NC;  rest /= NC;
    const int fn = rest % (F_ / 16);
    const int k  = rest / (F_ / 16);
    const int f = fn * 16 + (lane & 15);
    const int d = c * 32 + (lane >> 4) * 8;
    uint4 o;
    ushort_t* op = (ushort_t*)&o;
#pragma unroll
    for (int j = 0; j < 8; j++)
        op[j] = f2bf(w[((size_t)f * CIN + d + j) * 3 + k]);
    ((uint4*)p)[gid] = o;
}

// ---------------------------------------------------------------------------
// prep mega-kernel: all input-only work in ONE dispatch (validated round 5).
// ---------------------------------------------------------------------------
constexpr int NA_ = 144, NB_ = 96, NCB_ = 15, ND_ = R_ * D_ / 4 / 256, NE_ = B_;
constexpr int OFF_B = 2 * NA_;            // 288
constexpr int OFF_C = OFF_B + 2 * NB_;    // 480
constexpr int OFF_D = OFF_C + NCB_;       // 495
constexpr int OFF_E = OFF_D + ND_;        // 2031
constexpr int NPREP = OFF_E + NE_;        // 2047

__global__ __launch_bounds__(256) void prep_kernel(
    const float* __restrict__ dc0w, const float* __restrict__ pc0w,
    const float* __restrict__ dc1w, const float* __restrict__ pc1w,
    const float* __restrict__ projw,
    const float* __restrict__ enc_out, const float* __restrict__ pt,
    const float* __restrict__ we, const float* __restrict__ be,
    const int* __restrict__ dur,
    ushort_t* __restrict__ pw0d, ushort_t* __restrict__ pw0p,
    ushort_t* __restrict__ pw1d, ushort_t* __restrict__ pw1p,
    ushort_t* __restrict__ pwb, ushort_t* __restrict__ encb,
    int* __restrict__ idx_out, float* __restrict__ dec_mask)
{
    __shared__ int cums[T_];
    const int bx = blockIdx.x;

    if (bx < OFF_B) {                                   // job A
        if (bx < NA_) repack_job<D_>(bx, dc0w, pw0d);
        else          repack_job<D_>(bx - NA_, pc0w, pw0p);
    } else if (bx < OFF_C) {                            // job B
        const int b2 = bx - OFF_B;
        if (b2 < NB_) repack_job<F_>(b2, dc1w, pw1d);
        else          repack_job<F_>(b2 - NB_, pc1w, pw1p);
    } else if (bx < OFF_D) {                            // job C: proj repack
        const int gid = (bx - OFF_C) * 256 + threadIdx.x;  // over 3840
        const int lane = gid & 63;
        const int rest = gid >> 6;
        const int nt = rest % 5;
        const int c  = rest / 5;
        const int n = nt * 16 + (lane & 15);
        const int k = c * 32 + (lane >> 4) * 8;
        uint4 o;
        ushort_t* op = (ushort_t*)&o;
#pragma unroll
        for (int j = 0; j < 8; j++)
            op[j] = f2bf(projw[(size_t)n * D_ + k + j]);
        ((uint4*)pwb)[gid] = o;
    } else if (bx < OFF_E) {                            // job D: pitch add
        const int gid = (bx - OFF_D) * 256 + threadIdx.x;  // over R_*D_/4
        const int dq = gid % (D_ / 4);
        const int bt = gid / (D_ / 4);
        const int t = bt & 255, b = bt >> 8;
        const int d = dq * 4;
        const float4 e = ((const float4*)enc_out)[gid];
        const float p0 = (t > 0)   ? pt[b * T_ + t - 1] : 0.f;
        const float p1 = pt[b * T_ + t];
        const float p2 = (t < 255) ? pt[b * T_ + t + 1] : 0.f;
        const float* ev = (const float*)&e;
        ushort4 o;
        ushort_t* op = (ushort_t*)&o;
#pragma unroll
        for (int dd = 0; dd < 4; dd++) {
            float s = be[d + dd];
            s = fmaf(we[(d + dd) * 3 + 0], p0, s);
            s = fmaf(we[(d + dd) * 3 + 1], p1, s);
            s = fmaf(we[(d + dd) * 3 + 2], p2, s);
            op[dd] = f2bf(ev[dd] + s);
        }
        ((ushort4*)encb)[gid] = o;
    } else {                                            // job E: regulate
        const int b = bx - OFF_E, t = threadIdx.x;
        cums[t] = (int)rintf((float)dur[b * T_ + t] / PACE_);
        __syncthreads();
        for (int off = 1; off < T_; off <<= 1) {
            int v = cums[t];
            if (t >= off) v += cums[t - off];
            __syncthreads();
            cums[t] = v;
            __syncthreads();
        }
        const int dec_len = min(cums[T_ - 1], M_);
#pragma unroll
        for (int r = 0; r < M_ / T_; r++) {
            const int j = r * T_ + t;
            int lo = 0, hi = T_;
            while (lo < hi) {
                const int mid = (lo + hi) >> 1;
                if (cums[mid] <= j) lo = mid + 1; else hi = mid;
            }
            idx_out[b * M_ + j]  = min(lo, T_ - 1);
            dec_mask[b * M_ + j] = (j < dec_len) ? 1.f : 0.f;
        }
    }
}

// ---------------------------------------------------------------------------
// Conv1d(K=3,SAME)+bias+ReLU via MFMA 16x16x32, LDS-staged double-buffered B.
// Block: 32 rows x 128 f; grid (R_/32, F_/128, 2 z) = (128,2,2), 2 blocks/CU.
// Wave w: 2 m-tiles x 2 fn-tiles, tap-summed acc (4 chains). B chunk = 24 KB
// (3 taps x 8 fn x 1KB frag) staged by all 256 threads (6 uint4 each, bulk-
// issued -> L2 latency hidden), read back as contiguous ds_read_b128.
// ---------------------------------------------------------------------------
template <int CIN, bool FP32IN>
__global__ __launch_bounds__(256, 2) void conv_kernel(
    const void* __restrict__ in0, const void* __restrict__ in1,
    const float* __restrict__ mask,
    const ushort_t* __restrict__ pw0, const ushort_t* __restrict__ pw1,
    const float* __restrict__ bias0, const float* __restrict__ bias1,
    ushort_t* __restrict__ out0, ushort_t* __restrict__ out1)
{
    constexpr int LDX = CIN + 8;     // padded x row stride (bf16)
    constexpr int NC  = CIN / 32;
    __shared__ ushort_t xs[34 * LDX];
    __shared__ ushort_t Bs[2][24 * 512];   // 2 x 24 KB

    const int z = blockIdx.z;
    const void* in = z ? in1 : in0;
    const ushort_t* pw = z ? pw1 : pw0;
    const float* bias = z ? bias1 : bias0;
    ushort_t* out = z ? out1 : out0;

    const int fn0 = blockIdx.y * 8;        // 8 fn-tiles (128 f) per block
    const int r0  = blockIdx.x * 32;       // 32-row tiles never cross a batch
    const int bb  = r0 >> 8;
    const int tl  = r0 & 255;
    const int tid = threadIdx.x;

    // ---- stage x rows tl-1 .. tl+32 (34 rows), zero outside batch ----
    if (FP32IN) {
        const float* x = (const float*)in;
        for (int i = tid; i < 34 * (CIN / 8); i += 256) {
            const int row = i / (CIN / 8);
            const int dd  = (i - row * (CIN / 8)) * 8;
            const int t   = tl - 1 + row;
            ushort4 o0 = {0, 0, 0, 0}, o1 = {0, 0, 0, 0};
            if (t >= 0 && t < 256) {
                const float m = mask[bb * 256 + t];
                const float* xr = x + (size_t)(bb * 256 + t) * CIN + dd;
                const float4 v0 = *(const float4*)xr;
                const float4 v1 = *(const float4*)(xr + 4);
                o0.x = f2bf(v0.x * m); o0.y = f2bf(v0.y * m);
                o0.z = f2bf(v0.z * m); o0.w = f2bf(v0.w * m);
                o1.x = f2bf(v1.x * m); o1.y = f2bf(v1.y * m);
                o1.z = f2bf(v1.z * m); o1.w = f2bf(v1.w * m);
            }
            *(ushort4*)(&xs[row * LDX + dd])     = o0;
            *(ushort4*)(&xs[row * LDX + dd + 4]) = o1;
        }
    } else {
        const ushort_t* x = (const ushort_t*)in;
        for (int i = tid; i < 34 * (CIN / 8); i += 256) {
            const int row = i / (CIN / 8);
            const int dd  = (i - row * (CIN / 8)) * 8;
            const int t   = tl - 1 + row;
            uint4 v = make_uint4(0, 0, 0, 0);
            if (t >= 0 && t < 256)
                v = *(const uint4*)(x + (size_t)(bb * 256 + t) * CIN + dd);
            *(uint4*)(&xs[row * LDX + dd]) = v;
        }
    }

    // ---- B staging: chunk c = 24 tiles x 64 uint4; thread copies 6 uint4 ----
    const uint4* pw4 = (const uint4*)pw;
    uint4 breg[6];
    auto loadB = [&](int c) {
#pragma unroll
        for (int jj = 0; jj < 6; jj++) {
            const int u = jj * 256 + tid;
            const int tile = u >> 6, within = u & 63;
            const int tap = tile >> 3, fnl = tile & 7;
            breg[jj] = pw4[((size_t)((tap * 16 + fn0 + fnl) * NC + c) << 6) + within];
        }
    };
    auto storeB = [&](int buf) {
        uint4* d = (uint4*)Bs[buf];
#pragma unroll
        for (int jj = 0; jj < 6; jj++)
            d[jj * 256 + tid] = breg[jj];
    };
    loadB(0); storeB(0);
    __syncthreads();

    const int w = tid >> 6, l = tid & 63;
    const int q = l >> 4, lm = l & 15;
    const int fw = w * 2;                 // wave's local fn-tile base (of 8)

    f32x4_ acc[2][2];                     // [m][fl], taps summed in
#pragma unroll
    for (int m = 0; m < 2; m++)
#pragma unroll
        for (int fl = 0; fl < 2; fl++)
#pragma unroll
            for (int i = 0; i < 4; i++) acc[m][fl][i] = 0.f;

    for (int c = 0; c < NC; c++) {
        if (c + 1 < NC) loadB(c + 1);     // bulk global issue, overlap compute
        const int buf = c & 1;
        bf16x8 a[2][3];
#pragma unroll
        for (int m = 0; m < 2; m++)
#pragma unroll
            for (int tap = 0; tap < 3; tap++)
                a[m][tap] = *(const bf16x8*)(
                    &xs[(m * 16 + lm + tap) * LDX + c * 32 + q * 8]);
#pragma unroll
        for (int tap = 0; tap < 3; tap++) {
#pragma unroll
            for (int fl = 0; fl < 2; fl++) {
                const bf16x8 b = *(const bf16x8*)(
                    &Bs[buf][(tap * 8 + fw + fl) * 512 + l * 8]);
#pragma unroll
                for (int m = 0; m < 2; m++)
                    acc[m][fl] = __builtin_amdgcn_mfma_f32_16x16x32_bf16(
                        a[m][tap], b, acc[m][fl], 0, 0, 0);
            }
        }
        if (c + 1 < NC) storeB((c + 1) & 1);
        __syncthreads();
    }

    // ---- epilogue: bias + ReLU -> bf16.  C/D: col=lane&15, row=q*4+reg ----
#pragma unroll
    for (int fl = 0; fl < 2; fl++) {
        const int f = (fn0 + fw + fl) * 16 + lm;
        const float bs = bias[f];
#pragma unroll
        for (int m = 0; m < 2; m++) {
#pragma unroll
            for (int r = 0; r < 4; r++) {
                const int row = r0 + m * 16 + q * 4 + r;
                out[(size_t)row * F_ + f] = f2bf(fmaxf(acc[m][fl][r] + bs, 0.f));
            }
        }
    }
}

// ---------------------------------------------------------------------------
// LayerNorm over 256 channels, one wave per row, dur+pitch via blockIdx.y.
// (validated round 4)
// ---------------------------------------------------------------------------
__global__ __launch_bounds__(256) void ln2_kernel(
    const ushort_t* __restrict__ in0, const ushort_t* __restrict__ in1,
    const float* __restrict__ g0, const float* __restrict__ b0,
    const float* __restrict__ g1, const float* __restrict__ b1,
    ushort_t* __restrict__ o0, ushort_t* __restrict__ o1)
{
    const ushort_t* h = blockIdx.y ? in1 : in0;
    const float* g  = blockIdx.y ? g1 : g0;
    const float* be = blockIdx.y ? b1 : b0;
    ushort_t* o = blockIdx.y ? o1 : o0;

    const int row  = blockIdx.x * 4 + (threadIdx.x >> 6);
    const int lane = threadIdx.x & 63;
    const ushort4 hv = ((const ushort4*)(h + (size_t)row * F_))[lane];
    const float v0 = bf2f(hv.x), v1 = bf2f(hv.y), v2 = bf2f(hv.z), v3 = bf2f(hv.w);
    float sm = v0 + v1 + v2 + v3;
    float sq = v0 * v0 + v1 * v1 + v2 * v2 + v3 * v3;
#pragma unroll
    for (int off = 32; off >= 1; off >>= 1) {
        sm += __shfl_xor(sm, off);
        sq += __shfl_xor(sq, off);
    }
    const float mu = sm * (1.f / F_);
    const float rs = rsqrtf(sq * (1.f / F_) - mu * mu + 1e-5f);
    const float4 gv = ((const float4*)g)[lane];
    const float4 bv = ((const float4*)be)[lane];
    ushort4 ov;
    ov.x = f2bf((v0 - mu) * rs * gv.x + bv.x);
    ov.y = f2bf((v1 - mu) * rs * gv.y + bv.y);
    ov.z = f2bf((v2 - mu) * rs * gv.z + bv.z);
    ov.w = f2bf((v3 - mu) * rs * gv.w + bv.w);
    ((ushort4*)(o + (size_t)row * F_))[lane] = ov;
}

// ---------------------------------------------------------------------------
// Fused LayerNorm + FC head, one wave per row, dur+pitch via blockIdx.y.
// pred = (dot(LN(h), fcw) + fcb) * mask; z=0 also emits dur_pred.
// ---------------------------------------------------------------------------
__global__ __launch_bounds__(256) void lnfc_kernel(
    const ushort_t* __restrict__ in0, const ushort_t* __restrict__ in1,
    const float* __restrict__ g0, const float* __restrict__ b0,
    const float* __restrict__ g1, const float* __restrict__ b1,
    const float* __restrict__ w0, const float* __restrict__ w1,
    const float* __restrict__ cb0, const float* __restrict__ cb1,
    const float* __restrict__ mask,
    float* __restrict__ pred0, float* __restrict__ pred1,
    float* __restrict__ durpred)
{
    const int z = blockIdx.y;
    const ushort_t* h = z ? in1 : in0;
    const float* g   = z ? g1 : g0;
    const float* be  = z ? b1 : b0;
    const float* fcw = z ? w1 : w0;
    const float* fcb = z ? cb1 : cb0;
    float* pred = z ? pred1 : pred0;

    const int row  = blockIdx.x * 4 + (threadIdx.x >> 6);
    const int lane = threadIdx.x & 63;
    const ushort4 hv = ((const ushort4*)(h + (size_t)row * F_))[lane];
    const float v0 = bf2f(hv.x), v1 = bf2f(hv.y), v2 = bf2f(hv.z), v3 = bf2f(hv.w);
    float sm = v0 + v1 + v2 + v3;
    float sq = v0 * v0 + v1 * v1 + v2 * v2 + v3 * v3;
#pragma unroll
    for (int off = 32; off >= 1; off >>= 1) {
        sm += __shfl_xor(sm, off);
        sq += __shfl_xor(sq, off);
    }
    const float mu = sm * (1.f / F_);
    const float rs = rsqrtf(sq * (1.f / F_) - mu * mu + 1e-5f);
    const float4 gv = ((const float4*)g)[lane];
    const float4 bv = ((const float4*)be)[lane];
    const float4 wv = ((const float4*)fcw)[lane];
    float p = ((v0 - mu) * rs * gv.x + bv.x) * wv.x
            + ((v1 - mu) * rs * gv.y + bv.y) * wv.y
            + ((v2 - mu) * rs * gv.z + bv.z) * wv.z
            + ((v3 - mu) * rs * gv.w + bv.w) * wv.w;
#pragma unroll
    for (int off = 32; off >= 1; off >>= 1) p += __shfl_xor(p, off);
    if (lane == 0) {
        const float pp = (p + fcb[0]) * mask[row];
        pred[row] = pp;
        if (!z) durpred[row] = fminf(fmaxf(expf(pp) - 1.f, 0.f), MAXDUR_);
    }
}

// ---------------------------------------------------------------------------
// mel gather-GEMM via MFMA 16x16x32; full packed proj weight (60 KB) staged
// in LDS once per block; all 12 A-frags prefetched to registers.
// ---------------------------------------------------------------------------
__global__ __launch_bounds__(256, 2) void mel_mfma_kernel(
    const ushort_t* __restrict__ encb, const int* __restrict__ idx,
    const float* __restrict__ dmask, const ushort_t* __restrict__ pwb,
    const float* __restrict__ pb, float* __restrict__ mel)
{
    __shared__ ushort_t Bs[5 * 12 * 512];   // 61440 B
    __shared__ int ids[64];
    const int b  = blockIdx.y;
    const int j0 = blockIdx.x * 64;
    const int tid = threadIdx.x;

#pragma unroll
    for (int jj = 0; jj < 15; jj++)
        ((uint4*)Bs)[jj * 256 + tid] = ((const uint4*)pwb)[jj * 256 + tid];
    if (tid < 64) ids[tid] = idx[b * M_ + j0 + tid];
    __syncthreads();

    const int w = tid >> 6, l = tid & 63;
    const int q = l >> 4, lm = l & 15;
    const int row = ids[w * 16 + lm];
    const ushort_t* ap = encb + ((size_t)(b * 256 + row)) * D_ + q * 8;

    bf16x8 a[D_ / 32];
#pragma unroll
    for (int c = 0; c < D_ / 32; c++)       // 12 independent global loads
        a[c] = *(const bf16x8*)(ap + c * 32);

    f32x4_ acc[5];
#pragma unroll
    for (int nt = 0; nt < 5; nt++)
#pragma unroll
        for (int i = 0; i < 4; i++) acc[nt][i] = 0.f;

#pragma unroll
    for (int c = 0; c < D_ / 32; c++) {
#pragma unroll
        for (int nt = 0; nt < 5; nt++) {
            const bf16x8 bv = *(const bf16x8*)(&Bs[(c * 5 + nt) * 512 + l * 8]);
            acc[nt] = __builtin_amdgcn_mfma_f32_16x16x32_bf16(a[c], bv, acc[nt], 0, 0, 0);
        }
    }

    float msk[4];
#pragma unroll
    for (int r = 0; r < 4; r++)
        msk[r] = dmask[b * M_ + j0 + w * 16 + q * 4 + r];
#pragma unroll
    for (int nt = 0; nt < 5; nt++) {
        const int n = nt * 16 + lm;
        const float bb = pb[n];
#pragma unroll
        for (int r = 0; r < 4; r++) {
            const int j = j0 + w * 16 + q * 4 + r;
            mel[((size_t)b * M_ + j) * NMEL_ + n] = msk[r] * acc[nt][r] + bb;
        }
    }
}

// ---------------------------------------------------------------------------
extern "C" void kernel_launch(void* const* d_in, const int* in_sizes, int n_in,
                              void* d_out, int out_size, void* d_ws, size_t ws_size,
                              hipStream_t stream)
{
    const float* enc_out   = (const float*)d_in[0];
    const float* enc_mask  = (const float*)d_in[1];
    const float* pitch_tgt = (const float*)d_in[2];
    const int*   durations = (const int*)d_in[3];

    const float* dur_c0_w = (const float*)d_in[4];
    const float* dur_c0_b = (const float*)d_in[5];
    const float* dur_n0_g = (const float*)d_in[6];
    const float* dur_n0_b = (const float*)d_in[7];
    const float* dur_c1_w = (const float*)d_in[8];
    const float* dur_c1_b = (const float*)d_in[9];
    const float* dur_n1_g = (const float*)d_in[10];
    const float* dur_n1_b = (const float*)d_in[11];
    const float* dur_fc_w = (const float*)d_in[12];
    const float* dur_fc_b = (const float*)d_in[13];

    const float* pit_c0_w = (const float*)d_in[14];
    const float* pit_c0_b = (const float*)d_in[15];
    const float* pit_n0_g = (const float*)d_in[16];
    const float* pit_n0_b = (const float*)d_in[17];
    const float* pit_c1_w = (const float*)d_in[18];
    const float* pit_c1_b = (const float*)d_in[19];
    const float* pit_n1_g = (const float*)d_in[20];
    const float* pit_n1_b = (const float*)d_in[21];
    const float* pit_fc_w = (const float*)d_in[22];
    const float* pit_fc_b = (const float*)d_in[23];

    const float* pemb_w = (const float*)d_in[24];
    const float* pemb_b = (const float*)d_in[25];
    const float* proj_w = (const float*)d_in[26];
    const float* proj_b = (const float*)d_in[27];

    // Output slices (flat, in return order), all fp32.
    float* out       = (float*)d_out;
    float* mel_out   = out;                                   // [B,M,NMEL]
    float* dec_mask  = mel_out + (size_t)B_ * M_ * NMEL_;     // [B,M,1]
    float* dur_pred  = dec_mask + (size_t)B_ * M_;            // [B,T]
    float* log_dur   = dur_pred + (size_t)B_ * T_;            // [B,T]
    float* pitch_prd = log_dur + (size_t)B_ * T_;             // [B,T]

    // Workspace layout (~14 MiB)
    char* wp = (char*)d_ws;
    ushort_t* pw0d = (ushort_t*)wp; wp += (size_t)3 * F_ * D_ * 2;   // 590 KB
    ushort_t* pw0p = (ushort_t*)wp; wp += (size_t)3 * F_ * D_ * 2;
    ushort_t* pw1d = (ushort_t*)wp; wp += (size_t)3 * F_ * F_ * 2;   // 393 KB
    ushort_t* pw1p = (ushort_t*)wp; wp += (size_t)3 * F_ * F_ * 2;
    ushort_t* pwb  = (ushort_t*)wp; wp += (size_t)5 * 12 * 512 * 2;  // 61 KB
    ushort_t* encb = (ushort_t*)wp; wp += (size_t)R_ * D_ * 2;       // 3.15 MB
    ushort_t* h_d  = (ushort_t*)wp; wp += (size_t)R_ * F_ * 2;       // 2.10 MB
    ushort_t* h_p  = (ushort_t*)wp; wp += (size_t)R_ * F_ * 2;
    ushort_t* hb_d = (ushort_t*)wp; wp += (size_t)R_ * F_ * 2;
    ushort_t* hb_p = (ushort_t*)wp; wp += (size_t)R_ * F_ * 2;
    int*      idx  = (int*)wp;                                       // 131 KB

    const dim3 blk(256);
    const dim3 gconv(R_ / 32, F_ / 128, 2);   // (128, 2, 2)
    const dim3 grow(R_ / 4, 2);               // (1024, 2)

    // 1) all input-only prep in one dispatch
    prep_kernel<<<NPREP, blk, 0, stream>>>(
        dur_c0_w, pit_c0_w, dur_c1_w, pit_c1_w, proj_w,
        enc_out, pitch_tgt, pemb_w, pemb_b, durations,
        pw0d, pw0p, pw1d, pw1p, pwb, encb, idx, dec_mask);

    // 2) conv0 (dur & pitch), fp32 input with mask folded -> h (pre-LN)
    conv_kernel<D_, true><<<gconv, blk, 0, stream>>>(
        enc_out, enc_out, enc_mask, pw0d, pw0p, dur_c0_b, pit_c0_b, h_d, h_p);

    // 3) LN0 -> hb
    ln2_kernel<<<grow, blk, 0, stream>>>(
        h_d, h_p, dur_n0_g, dur_n0_b, pit_n0_g, pit_n0_b, hb_d, hb_p);

    // 4) conv1 (dur & pitch), bf16 input -> h (pre-LN)
    conv_kernel<F_, false><<<gconv, blk, 0, stream>>>(
        hb_d, hb_p, enc_mask, pw1d, pw1p, dur_c1_b, pit_c1_b, h_d, h_p);

    // 5) LN1 + FC heads -> predictions
    lnfc_kernel<<<grow, blk, 0, stream>>>(
        h_d, h_p, dur_n1_g, dur_n1_b, pit_n1_g, pit_n1_b,
        dur_fc_w, pit_fc_w, dur_fc_b, pit_fc_b, enc_mask,
        log_dur, pitch_prd, dur_pred);

    // 6) gather + projection to mel
    mel_mfma_kernel<<<dim3(M_ / 64, B_), blk, 0, stream>>>(
        encb, idx, dec_mask, pwb, proj_b, mel_out);
}

// Round 7
// 184.742 us; speedup vs baseline: 1.1365x; 1.1365x over previous
//
#include <hip/hip_runtime.h>
#include <math.h>

// Problem constants (from reference)
constexpr int B_ = 16, T_ = 256, D_ = 384, M_ = 2048, F_ = 256, NMEL_ = 80;
constexpr float PACE_ = 1.0f, MAXDUR_ = 75.0f;
constexpr int R_ = B_ * T_;  // 4096 total rows

typedef unsigned short ushort_t;
typedef __attribute__((ext_vector_type(8))) short bf16x8;
typedef __attribute__((ext_vector_type(4))) float f32x4_;

static __device__ __forceinline__ ushort_t f2bf(float x) {
    union { float f; unsigned int u; } v; v.f = x;
    const unsigned int r = v.u + 0x7fffu + ((v.u >> 16) & 1u);  // RNE
    return (ushort_t)(r >> 16);
}
static __device__ __forceinline__ float bf2f(ushort_t h) {
    union { float f; unsigned int u; } v; v.u = ((unsigned int)h) << 16;
    return v.f;
}

// ---------------------------------------------------------------------------
// Weight repack device job: w[F_,CIN,3] fp32 -> bf16 16x16x32 B-frag order:
//   p[ ((k*(F_/16)+fn)*(CIN/32)+c)*512 + lane*8 + j ]
//     = w[f=fn*16+(lane&15)][d=c*32+(lane>>4)*8+j][k]   (validated r4-r6)
// ---------------------------------------------------------------------------
template <int CIN>
static __device__ void repack_job(int bx, const float* __restrict__ w,
                                  ushort_t* __restrict__ p)
{
    constexpr int NC = CIN / 32;
    const int gid = bx * 256 + threadIdx.x;   // over 3*F_*CIN/8
    const int lane = gid & 63;
    int rest = gid >> 6;
    const int c = rest % NC;  rest /= NC;
    const int fn = rest % (F_ / 16);
    const int k  = rest / (F_ / 16);
    const int f = fn * 16 + (lane & 15);
    const int d = c * 32 + (lane >> 4) * 8;
    uint4 o;
    ushort_t* op = (ushort_t*)&o;
#pragma unroll
    for (int j = 0; j < 8; j++)
        op[j] = f2bf(w[((size_t)f * CIN + d + j) * 3 + k]);
    ((uint4*)p)[gid] = o;
}

// ---------------------------------------------------------------------------
// prep mega-kernel: all input-only work in ONE dispatch.
//  job D additionally emits xb = bf16(enc_out * mask)  (conv0 input, cast once)
// ---------------------------------------------------------------------------
constexpr int NA_ = 144, NB_ = 96, NCB_ = 15, ND_ = R_ * D_ / 4 / 256, NE_ = B_;
constexpr int OFF_B = 2 * NA_;            // 288
constexpr int OFF_C = OFF_B + 2 * NB_;    // 480
constexpr int OFF_D = OFF_C + NCB_;       // 495
constexpr int OFF_E = OFF_D + ND_;        // 2031
constexpr int NPREP = OFF_E + NE_;        // 2047

__global__ __launch_bounds__(256) void prep_kernel(
    const float* __restrict__ dc0w, const float* __restrict__ pc0w,
    const float* __restrict__ dc1w, const float* __restrict__ pc1w,
    const float* __restrict__ projw,
    const float* __restrict__ enc_out, const float* __restrict__ maskp,
    const float* __restrict__ pt,
    const float* __restrict__ we, const float* __restrict__ be,
    const int* __restrict__ dur,
    ushort_t* __restrict__ pw0d, ushort_t* __restrict__ pw0p,
    ushort_t* __restrict__ pw1d, ushort_t* __restrict__ pw1p,
    ushort_t* __restrict__ pwb, ushort_t* __restrict__ encb,
    ushort_t* __restrict__ xb,
    int* __restrict__ idx_out, float* __restrict__ dec_mask)
{
    __shared__ int cums[T_];
    const int bx = blockIdx.x;

    if (bx < OFF_B) {                                   // job A
        if (bx < NA_) repack_job<D_>(bx, dc0w, pw0d);
        else          repack_job<D_>(bx - NA_, pc0w, pw0p);
    } else if (bx < OFF_C) {                            // job B
        const int b2 = bx - OFF_B;
        if (b2 < NB_) repack_job<F_>(b2, dc1w, pw1d);
        else          repack_job<F_>(b2 - NB_, pc1w, pw1p);
    } else if (bx < OFF_D) {                            // job C: proj repack
        const int gid = (bx - OFF_C) * 256 + threadIdx.x;  // over 3840
        const int lane = gid & 63;
        const int rest = gid >> 6;
        const int nt = rest % 5;
        const int c  = rest / 5;
        const int n = nt * 16 + (lane & 15);
        const int k = c * 32 + (lane >> 4) * 8;
        uint4 o;
        ushort_t* op = (ushort_t*)&o;
#pragma unroll
        for (int j = 0; j < 8; j++)
            op[j] = f2bf(projw[(size_t)n * D_ + k + j]);
        ((uint4*)pwb)[gid] = o;
    } else if (bx < OFF_E) {                            // job D: pitch add + xb cast
        const int gid = (bx - OFF_D) * 256 + threadIdx.x;  // over R_*D_/4
        const int dq = gid % (D_ / 4);
        const int bt = gid / (D_ / 4);
        const int t = bt & 255, b = bt >> 8;
        const int d = dq * 4;
        const float4 e = ((const float4*)enc_out)[gid];
        const float m  = maskp[b * T_ + t];
        const float p0 = (t > 0)   ? pt[b * T_ + t - 1] : 0.f;
        const float p1 = pt[b * T_ + t];
        const float p2 = (t < 255) ? pt[b * T_ + t + 1] : 0.f;
        const float* ev = (const float*)&e;
        ushort4 o, ox;
        ushort_t* op = (ushort_t*)&o;
        ushort_t* oxp = (ushort_t*)&ox;
#pragma unroll
        for (int dd = 0; dd < 4; dd++) {
            float s = be[d + dd];
            s = fmaf(we[(d + dd) * 3 + 0], p0, s);
            s = fmaf(we[(d + dd) * 3 + 1], p1, s);
            s = fmaf(we[(d + dd) * 3 + 2], p2, s);
            op[dd]  = f2bf(ev[dd] + s);
            oxp[dd] = f2bf(ev[dd] * m);
        }
        ((ushort4*)encb)[gid] = o;
        ((ushort4*)xb)[gid]   = ox;
    } else {                                            // job E: regulate
        const int b = bx - OFF_E, t = threadIdx.x;
        cums[t] = (int)rintf((float)dur[b * T_ + t] / PACE_);
        __syncthreads();
        for (int off = 1; off < T_; off <<= 1) {
            int v = cums[t];
            if (t >= off) v += cums[t - off];
            __syncthreads();
            cums[t] = v;
            __syncthreads();
        }
        const int dec_len = min(cums[T_ - 1], M_);
#pragma unroll
        for (int r = 0; r < M_ / T_; r++) {
            const int j = r * T_ + t;
            int lo = 0, hi = T_;
            while (lo < hi) {
                const int mid = (lo + hi) >> 1;
                if (cums[mid] <= j) lo = mid + 1; else hi = mid;
            }
            idx_out[b * M_ + j]  = min(lo, T_ - 1);
            dec_mask[b * M_ + j] = (j < dec_len) ? 1.f : 0.f;
        }
    }
}

// ---------------------------------------------------------------------------
// Conv1d(K=3,SAME)+bias+ReLU as m97-shaped MFMA GEMM.
// Block: 64 rows x 128 f; grid (R_/64, F_/128, 2z) = (64,2,2) = 256 blocks.
// Per K-chunk (32): A (66x32 halo tile) AND B (24 frags = 24 KB) double-
// buffered in LDS; wave = 2 m-tiles x 4 fn-tiles x 3 taps = 24 MFMAs per
// chunk from 18 ds_read_b128 (~0.75 KB/MFMA). Epilogue routes acc through
// LDS -> 16B/lane coalesced global stores (kills write amplification).
// ---------------------------------------------------------------------------
template <int CIN>
__global__ __launch_bounds__(256) void conv_kernel(
    const ushort_t* __restrict__ in0, const ushort_t* __restrict__ in1,
    const ushort_t* __restrict__ pw0, const ushort_t* __restrict__ pw1,
    const float* __restrict__ bias0, const float* __restrict__ bias1,
    ushort_t* __restrict__ out0, ushort_t* __restrict__ out1)
{
    constexpr int NC = CIN / 32;
    // LDS: A dbuf 2x5280 ushort (66 rows x 40-stride) + B dbuf 2x12288 ushort
    __shared__ __align__(16) char smem[70272];
    ushort_t* Asm = (ushort_t*)smem;             // [2][5280]
    ushort_t* Bsm = (ushort_t*)(smem + 21120);   // [2][12288]

    const int z = blockIdx.z;
    const ushort_t* x  = z ? in1 : in0;
    const ushort_t* pw = z ? pw1 : pw0;
    const float* bias  = z ? bias1 : bias0;
    ushort_t* out      = z ? out1 : out0;

    const int r0 = blockIdx.x * 64;      // 64-row tiles never cross a batch
    const int bb = r0 >> 8;
    const int tl = r0 & 255;
    const int fb = blockIdx.y * 8;       // fn-tile base (8 tiles = 128 f)
    const int tid = threadIdx.x;

    uint4 areg0, areg1;
    uint4 breg[6];

    auto loadA = [&](int c) {
        {   const int row = tid >> 2, jc = (tid & 3) * 8;
            const int t = tl - 1 + row;
            areg0 = make_uint4(0u, 0u, 0u, 0u);
            if (t >= 0 && t < 256)
                areg0 = *(const uint4*)(x + (size_t)(bb * 256 + t) * CIN + c * 32 + jc);
        }
        if (tid < 8) {
            const int u = 256 + tid;
            const int row = u >> 2, jc = (u & 3) * 8;
            const int t = tl - 1 + row;
            areg1 = make_uint4(0u, 0u, 0u, 0u);
            if (t >= 0 && t < 256)
                areg1 = *(const uint4*)(x + (size_t)(bb * 256 + t) * CIN + c * 32 + jc);
        }
    };
    auto storeA = [&](int buf) {
        ushort_t* d = Asm + buf * 5280;
        *(uint4*)(d + (tid >> 2) * 40 + (tid & 3) * 8) = areg0;
        if (tid < 8) {
            const int u = 256 + tid;
            *(uint4*)(d + (u >> 2) * 40 + (u & 3) * 8) = areg1;
        }
    };
    auto loadB = [&](int c) {
#pragma unroll
        for (int jj = 0; jj < 6; jj++) {
            const int u = jj * 256 + tid;
            const int frag = u >> 6, within = u & 63;
            const int tap = frag >> 3, fnl = frag & 7;
            breg[jj] = *(const uint4*)(
                pw + (((size_t)(tap * 16 + fb + fnl) * NC + c) << 9) + within * 8);
        }
    };
    auto storeB = [&](int buf) {
        ushort_t* d = Bsm + buf * 12288;
#pragma unroll
        for (int jj = 0; jj < 6; jj++) {
            const int u = jj * 256 + tid;
            *(uint4*)(d + u * 8) = breg[jj];
        }
    };

    loadA(0); loadB(0); storeA(0); storeB(0);
    __syncthreads();

    const int w = tid >> 6, l = tid & 63;
    const int wy = w >> 1, wx = w & 1;   // m-half, fn-half
    const int q = l >> 4, lm = l & 15;

    f32x4_ acc[2][4];
#pragma unroll
    for (int mi = 0; mi < 2; mi++)
#pragma unroll
        for (int nf = 0; nf < 4; nf++)
#pragma unroll
            for (int i = 0; i < 4; i++) acc[mi][nf][i] = 0.f;

    for (int c = 0; c < NC; c++) {
        const int buf = c & 1;
        if (c + 1 < NC) { loadA(c + 1); loadB(c + 1); }

        const ushort_t* Ab = Asm + buf * 5280;
        const ushort_t* Bb = Bsm + buf * 12288;
        bf16x8 a[2][3], b[4][3];
#pragma unroll
        for (int mi = 0; mi < 2; mi++)
#pragma unroll
            for (int tap = 0; tap < 3; tap++)
                a[mi][tap] = *(const bf16x8*)(
                    Ab + ((wy * 2 + mi) * 16 + lm + tap) * 40 + q * 8);
#pragma unroll
        for (int nf = 0; nf < 4; nf++)
#pragma unroll
            for (int tap = 0; tap < 3; tap++)
                b[nf][tap] = *(const bf16x8*)(
                    Bb + (tap * 8 + wx * 4 + nf) * 512 + l * 8);
#pragma unroll
        for (int tap = 0; tap < 3; tap++)
#pragma unroll
            for (int nf = 0; nf < 4; nf++)
#pragma unroll
                for (int mi = 0; mi < 2; mi++)
                    acc[mi][nf] = __builtin_amdgcn_mfma_f32_16x16x32_bf16(
                        a[mi][tap], b[nf][tap], acc[mi][nf], 0, 0, 0);

        if (c + 1 < NC) { storeA((c + 1) & 1); storeB((c + 1) & 1); }
        __syncthreads();
    }

    // ---- epilogue: acc -> LDS h-tile (bf16) -> coalesced 16B stores ----
    ushort_t* hs = (ushort_t*)smem;      // 64 x 136 ushort = 17408 B overlay
    const int fbase = fb * 16;           // blockIdx.y * 128
#pragma unroll
    for (int nf = 0; nf < 4; nf++) {
        const int fl = (wx * 4 + nf) * 16 + lm;
        const float bs = bias[fbase + fl];
#pragma unroll
        for (int mi = 0; mi < 2; mi++)
#pragma unroll
            for (int r = 0; r < 4; r++) {
                const int row = (wy * 2 + mi) * 16 + q * 4 + r;
                hs[row * 136 + fl] = f2bf(fmaxf(acc[mi][nf][r] + bs, 0.f));
            }
    }
    __syncthreads();
#pragma unroll
    for (int p = 0; p < 4; p++) {
        const int u = p * 256 + tid;     // 1024 units of 16 B
        const int row = u >> 4, fo = (u & 15) * 8;
        *(uint4*)(out + (size_t)(r0 + row) * F_ + fbase + fo) =
            *(const uint4*)(hs + row * 136 + fo);
    }
}

// ---------------------------------------------------------------------------
// LayerNorm over 256 channels; 2 rows per wave (16B loads), dur+pitch via y.
// ---------------------------------------------------------------------------
__global__ __launch_bounds__(256) void ln2_kernel(
    const ushort_t* __restrict__ in0, const ushort_t* __restrict__ in1,
    const float* __restrict__ g0, const float* __restrict__ b0,
    const float* __restrict__ g1, const float* __restrict__ b1,
    ushort_t* __restrict__ o0, ushort_t* __restrict__ o1)
{
    const int z = blockIdx.y;
    const ushort_t* h = z ? in1 : in0;
    const float* g  = z ? g1 : g0;
    const float* be = z ? b1 : b0;
    ushort_t* o = z ? o1 : o0;

    const int wv = threadIdx.x >> 6, lane = threadIdx.x & 63;
    const int half = lane >> 5, lh = lane & 31;
    const int row = blockIdx.x * 8 + wv * 2 + half;

    uint4 hv4 = *(const uint4*)(h + (size_t)row * F_ + lh * 8);
    const ushort_t* hp = (const ushort_t*)&hv4;
    float v[8], sm = 0.f, sq = 0.f;
#pragma unroll
    for (int j = 0; j < 8; j++) { v[j] = bf2f(hp[j]); sm += v[j]; sq += v[j] * v[j]; }
#pragma unroll
    for (int off = 16; off >= 1; off >>= 1) {
        sm += __shfl_xor(sm, off);
        sq += __shfl_xor(sq, off);
    }
    const float mu = sm * (1.f / F_);
    const float rs = rsqrtf(sq * (1.f / F_) - mu * mu + 1e-5f);
    const float4 gv0 = ((const float4*)g)[lh * 2], gv1 = ((const float4*)g)[lh * 2 + 1];
    const float4 bv0 = ((const float4*)be)[lh * 2], bv1 = ((const float4*)be)[lh * 2 + 1];
    const float* gp = (const float*)&gv0;   // gv0/gv1 adjacent? use arrays
    float gg[8] = {gv0.x, gv0.y, gv0.z, gv0.w, gv1.x, gv1.y, gv1.z, gv1.w};
    float bbv[8] = {bv0.x, bv0.y, bv0.z, bv0.w, bv1.x, bv1.y, bv1.z, bv1.w};
    (void)gp;
    uint4 ov;
    ushort_t* op = (ushort_t*)&ov;
#pragma unroll
    for (int j = 0; j < 8; j++)
        op[j] = f2bf((v[j] - mu) * rs * gg[j] + bbv[j]);
    *(uint4*)(o + (size_t)row * F_ + lh * 8) = ov;
}

// ---------------------------------------------------------------------------
// Fused LayerNorm + FC head; 2 rows per wave, dur+pitch via blockIdx.y.
// ---------------------------------------------------------------------------
__global__ __launch_bounds__(256) void lnfc_kernel(
    const ushort_t* __restrict__ in0, const ushort_t* __restrict__ in1,
    const float* __restrict__ g0, const float* __restrict__ b0,
    const float* __restrict__ g1, const float* __restrict__ b1,
    const float* __restrict__ w0, const float* __restrict__ w1,
    const float* __restrict__ cb0, const float* __restrict__ cb1,
    const float* __restrict__ mask,
    float* __restrict__ pred0, float* __restrict__ pred1,
    float* __restrict__ durpred)
{
    const int z = blockIdx.y;
    const ushort_t* h = z ? in1 : in0;
    const float* g   = z ? g1 : g0;
    const float* be  = z ? b1 : b0;
    const float* fcw = z ? w1 : w0;
    const float* fcb = z ? cb1 : cb0;
    float* pred = z ? pred1 : pred0;

    const int wv = threadIdx.x >> 6, lane = threadIdx.x & 63;
    const int half = lane >> 5, lh = lane & 31;
    const int row = blockIdx.x * 8 + wv * 2 + half;

    uint4 hv4 = *(const uint4*)(h + (size_t)row * F_ + lh * 8);
    const ushort_t* hp = (const ushort_t*)&hv4;
    float v[8], sm = 0.f, sq = 0.f;
#pragma unroll
    for (int j = 0; j < 8; j++) { v[j] = bf2f(hp[j]); sm += v[j]; sq += v[j] * v[j]; }
#pragma unroll
    for (int off = 16; off >= 1; off >>= 1) {
        sm += __shfl_xor(sm, off);
        sq += __shfl_xor(sq, off);
    }
    const float mu = sm * (1.f / F_);
    const float rs = rsqrtf(sq * (1.f / F_) - mu * mu + 1e-5f);
    const float4 gv0 = ((const float4*)g)[lh * 2], gv1 = ((const float4*)g)[lh * 2 + 1];
    const float4 bv0 = ((const float4*)be)[lh * 2], bv1 = ((const float4*)be)[lh * 2 + 1];
    const float4 wv0 = ((const float4*)fcw)[lh * 2], wv1 = ((const float4*)fcw)[lh * 2 + 1];
    const float gg[8] = {gv0.x, gv0.y, gv0.z, gv0.w, gv1.x, gv1.y, gv1.z, gv1.w};
    const float bbv[8] = {bv0.x, bv0.y, bv0.z, bv0.w, bv1.x, bv1.y, bv1.z, bv1.w};
    const float ww[8] = {wv0.x, wv0.y, wv0.z, wv0.w, wv1.x, wv1.y, wv1.z, wv1.w};
    float p = 0.f;
#pragma unroll
    for (int j = 0; j < 8; j++)
        p += ((v[j] - mu) * rs * gg[j] + bbv[j]) * ww[j];
#pragma unroll
    for (int off = 16; off >= 1; off >>= 1) p += __shfl_xor(p, off);
    if (lh == 0) {
        const float pp = (p + fcb[0]) * mask[row];
        pred[row] = pp;
        if (!z) durpred[row] = fminf(fmaxf(expf(pp) - 1.f, 0.f), MAXDUR_);
    }
}

// ---------------------------------------------------------------------------
// mel gather-GEMM via MFMA 16x16x32 (validated r5/r6): packed proj weight
// (60 KB) LDS-resident per block; 12 A-frags prefetched to registers.
// ---------------------------------------------------------------------------
__global__ __launch_bounds__(256, 2) void mel_mfma_kernel(
    const ushort_t* __restrict__ encb, const int* __restrict__ idx,
    const float* __restrict__ dmask, const ushort_t* __restrict__ pwb,
    const float* __restrict__ pb, float* __restrict__ mel)
{
    __shared__ ushort_t Bs[5 * 12 * 512];   // 61440 B
    __shared__ int ids[64];
    const int b  = blockIdx.y;
    const int j0 = blockIdx.x * 64;
    const int tid = threadIdx.x;

#pragma unroll
    for (int jj = 0; jj < 15; jj++)
        ((uint4*)Bs)[jj * 256 + tid] = ((const uint4*)pwb)[jj * 256 + tid];
    if (tid < 64) ids[tid] = idx[b * M_ + j0 + tid];
    __syncthreads();

    const int w = tid >> 6, l = tid & 63;
    const int q = l >> 4, lm = l & 15;
    const int row = ids[w * 16 + lm];
    const ushort_t* ap = encb + ((size_t)(b * 256 + row)) * D_ + q * 8;

    bf16x8 a[D_ / 32];
#pragma unroll
    for (int c = 0; c < D_ / 32; c++)
        a[c] = *(const bf16x8*)(ap + c * 32);

    f32x4_ acc[5];
#pragma unroll
    for (int nt = 0; nt < 5; nt++)
#pragma unroll
        for (int i = 0; i < 4; i++) acc[nt][i] = 0.f;

#pragma unroll
    for (int c = 0; c < D_ / 32; c++) {
#pragma unroll
        for (int nt = 0; nt < 5; nt++) {
            const bf16x8 bv = *(const bf16x8*)(&Bs[(c * 5 + nt) * 512 + l * 8]);
            acc[nt] = __builtin_amdgcn_mfma_f32_16x16x32_bf16(a[c], bv, acc[nt], 0, 0, 0);
        }
    }

    float msk[4];
#pragma unroll
    for (int r = 0; r < 4; r++)
        msk[r] = dmask[b * M_ + j0 + w * 16 + q * 4 + r];
#pragma unroll
    for (int nt = 0; nt < 5; nt++) {
        const int n = nt * 16 + lm;
        const float bb = pb[n];
#pragma unroll
        for (int r = 0; r < 4; r++) {
            const int j = j0 + w * 16 + q * 4 + r;
            mel[((size_t)b * M_ + j) * NMEL_ + n] = msk[r] * acc[nt][r] + bb;
        }
    }
}

// ---------------------------------------------------------------------------
extern "C" void kernel_launch(void* const* d_in, const int* in_sizes, int n_in,
                              void* d_out, int out_size, void* d_ws, size_t ws_size,
                              hipStream_t stream)
{
    const float* enc_out   = (const float*)d_in[0];
    const float* enc_mask  = (const float*)d_in[1];
    const float* pitch_tgt = (const float*)d_in[2];
    const int*   durations = (const int*)d_in[3];

    const float* dur_c0_w = (const float*)d_in[4];
    const float* dur_c0_b = (const float*)d_in[5];
    const float* dur_n0_g = (const float*)d_in[6];
    const float* dur_n0_b = (const float*)d_in[7];
    const float* dur_c1_w = (const float*)d_in[8];
    const float* dur_c1_b = (const float*)d_in[9];
    const float* dur_n1_g = (const float*)d_in[10];
    const float* dur_n1_b = (const float*)d_in[11];
    const float* dur_fc_w = (const float*)d_in[12];
    const float* dur_fc_b = (const float*)d_in[13];

    const float* pit_c0_w = (const float*)d_in[14];
    const float* pit_c0_b = (const float*)d_in[15];
    const float* pit_n0_g = (const float*)d_in[16];
    const float* pit_n0_b = (const float*)d_in[17];
    const float* pit_c1_w = (const float*)d_in[18];
    const float* pit_c1_b = (const float*)d_in[19];
    const float* pit_n1_g = (const float*)d_in[20];
    const float* pit_n1_b = (const float*)d_in[21];
    const float* pit_fc_w = (const float*)d_in[22];
    const float* pit_fc_b = (const float*)d_in[23];

    const float* pemb_w = (const float*)d_in[24];
    const float* pemb_b = (const float*)d_in[25];
    const float* proj_w = (const float*)d_in[26];
    const float* proj_b = (const float*)d_in[27];

    // Output slices (flat, in return order), all fp32.
    float* out       = (float*)d_out;
    float* mel_out   = out;                                   // [B,M,NMEL]
    float* dec_mask  = mel_out + (size_t)B_ * M_ * NMEL_;     // [B,M,1]
    float* dur_pred  = dec_mask + (size_t)B_ * M_;            // [B,T]
    float* log_dur   = dur_pred + (size_t)B_ * T_;            // [B,T]
    float* pitch_prd = log_dur + (size_t)B_ * T_;             // [B,T]

    // Workspace layout (~17 MiB)
    char* wp = (char*)d_ws;
    ushort_t* pw0d = (ushort_t*)wp; wp += (size_t)3 * F_ * D_ * 2;   // 590 KB
    ushort_t* pw0p = (ushort_t*)wp; wp += (size_t)3 * F_ * D_ * 2;
    ushort_t* pw1d = (ushort_t*)wp; wp += (size_t)3 * F_ * F_ * 2;   // 393 KB
    ushort_t* pw1p = (ushort_t*)wp; wp += (size_t)3 * F_ * F_ * 2;
    ushort_t* pwb  = (ushort_t*)wp; wp += (size_t)5 * 12 * 512 * 2;  // 61 KB
    ushort_t* encb = (ushort_t*)wp; wp += (size_t)R_ * D_ * 2;       // 3.15 MB
    ushort_t* xb   = (ushort_t*)wp; wp += (size_t)R_ * D_ * 2;       // 3.15 MB
    ushort_t* h_d  = (ushort_t*)wp; wp += (size_t)R_ * F_ * 2;       // 2.10 MB
    ushort_t* h_p  = (ushort_t*)wp; wp += (size_t)R_ * F_ * 2;
    ushort_t* hb_d = (ushort_t*)wp; wp += (size_t)R_ * F_ * 2;
    ushort_t* hb_p = (ushort_t*)wp; wp += (size_t)R_ * F_ * 2;
    int*      idx  = (int*)wp;                                       // 131 KB

    const dim3 blk(256);
    const dim3 gconv(R_ / 64, 2, 2);          // (64, 2, 2) = 256 blocks
    const dim3 grow(R_ / 8, 2);               // (512, 2)

    // 1) all input-only prep (weight repacks, encb, xb cast, regulate)
    prep_kernel<<<NPREP, blk, 0, stream>>>(
        dur_c0_w, pit_c0_w, dur_c1_w, pit_c1_w, proj_w,
        enc_out, enc_mask, pitch_tgt, pemb_w, pemb_b, durations,
        pw0d, pw0p, pw1d, pw1p, pwb, encb, xb, idx, dec_mask);

    // 2) conv0 (dur & pitch), bf16 input -> h (pre-LN)
    conv_kernel<D_><<<gconv, blk, 0, stream>>>(
        xb, xb, pw0d, pw0p, dur_c0_b, pit_c0_b, h_d, h_p);

    // 3) LN0 -> hb
    ln2_kernel<<<grow, blk, 0, stream>>>(
        h_d, h_p, dur_n0_g, dur_n0_b, pit_n0_g, pit_n0_b, hb_d, hb_p);

    // 4) conv1 (dur & pitch), bf16 input -> h (pre-LN)
    conv_kernel<F_><<<gconv, blk, 0, stream>>>(
        hb_d, hb_p, pw1d, pw1p, dur_c1_b, pit_c1_b, h_d, h_p);

    // 5) LN1 + FC heads -> predictions
    lnfc_kernel<<<grow, blk, 0, stream>>>(
        h_d, h_p, dur_n1_g, dur_n1_b, pit_n1_g, pit_n1_b,
        dur_fc_w, pit_fc_w, dur_fc_b, pit_fc_b, enc_mask,
        log_dur, pitch_prd, dur_pred);

    // 6) gather + projection to mel
    mel_mfma_kernel<<<dim3(M_ / 64, B_), blk, 0, stream>>>(
        encb, idx, dec_mask, pwb, proj_b, mel_out);
}